// Round 1
// baseline (1550.882 us; speedup 1.0000x reference)
//
#include <hip/hip_runtime.h>
#include <hip/hip_bf16.h>

// Problem constants (hardcoded to the reference shapes)
#define B_Q 64
#define D_K 768
#define N_K 262144
#define V_SZ 50257
#define KNN_K 8
#define TEMP_INV 0.1f
#define LAM 0.25f
#define EPS_KNN 1e-10f

typedef __bf16  bf16x8 __attribute__((ext_vector_type(8)));
typedef float   f32x4  __attribute__((ext_vector_type(4)));
typedef _Float16 f16x8 __attribute__((ext_vector_type(8)));

static __device__ __forceinline__ unsigned long long umin64(unsigned long long a,
                                                            unsigned long long b) {
  return a < b ? a : b;
}

// order-preserving float -> uint key (works for any sign)
static __device__ __forceinline__ unsigned int fkey(float v) {
  unsigned int u = __float_as_uint(v);
  return u ^ ((u >> 31) ? 0xFFFFFFFFu : 0x80000000u);
}

// ---------------------------------------------------------------------------
// K1: convert queries f32 -> bf16 (row-major [64][768])
// ---------------------------------------------------------------------------
__global__ __launch_bounds__(256) void k_cvt(const float* __restrict__ q,
                                             __bf16* __restrict__ qbf) {
  int i = blockIdx.x * 256 + threadIdx.x;   // grid exactly covers 64*768
  qbf[i] = (__bf16)q[i];
}

// ---------------------------------------------------------------------------
// K2: streaming pass. scores[b][n] = ||k_n||^2 - 2 q_b . k_n - 768 (f16, approx)
// WG = 256 (4 waves); wave w owns query tile [16w,16w+16); 8 N-tiles of 16 keys.
// Keys read straight from global as MFMA B-fragments (8 consecutive f32/lane).
// ---------------------------------------------------------------------------
__global__ __launch_bounds__(256) void k_gemm(const float* __restrict__ keys,
                                              const __bf16* __restrict__ qbf,
                                              _Float16* __restrict__ scores) {
  const int tid  = threadIdx.x;
  const int wave = tid >> 6;
  const int lane = tid & 63;
  const int r16  = lane & 15;   // B: key row in tile / A: query row in tile
  const int grp  = lane >> 4;   // 0..3

  // A fragments for all 24 k-steps: A[m=lane&15][k=grp*8+j], 96 VGPRs
  bf16x8 afrag[24];
  {
    const __bf16* qp = qbf + (size_t)(wave * 16 + r16) * D_K + grp * 8;
#pragma unroll
    for (int t = 0; t < 24; ++t)
      afrag[t] = *reinterpret_cast<const bf16x8*>(qp + t * 32);
  }

  const int tile0 = blockIdx.x * 8;
  for (int tt = 0; tt < 8; ++tt) {
    const int n0 = (tile0 + tt) * 16;
    const float* kp = keys + (size_t)(n0 + r16) * D_K + grp * 8;
    f32x4 acc = {0.f, 0.f, 0.f, 0.f};
    float k2 = 0.f;
#pragma unroll
    for (int ks = 0; ks < 24; ++ks) {
      const float4 x0 = *reinterpret_cast<const float4*>(kp + ks * 32);
      const float4 x1 = *reinterpret_cast<const float4*>(kp + ks * 32 + 4);
      bf16x8 bfrag;
      bfrag[0] = (__bf16)x0.x; bfrag[1] = (__bf16)x0.y;
      bfrag[2] = (__bf16)x0.z; bfrag[3] = (__bf16)x0.w;
      bfrag[4] = (__bf16)x1.x; bfrag[5] = (__bf16)x1.y;
      bfrag[6] = (__bf16)x1.z; bfrag[7] = (__bf16)x1.w;
      k2 += x0.x * x0.x + x0.y * x0.y + x0.z * x0.z + x0.w * x0.w
          + x1.x * x1.x + x1.y * x1.y + x1.z * x1.z + x1.w * x1.w;
      acc = __builtin_amdgcn_mfma_f32_16x16x32_bf16(afrag[ks], bfrag, acc, 0, 0, 0);
    }
    // full ||k||^2: combine the 4 lane-groups that share this key row
    k2 += __shfl_xor(k2, 16);
    k2 += __shfl_xor(k2, 32);
    // C/D layout: col(n)=lane&15, row(m)=grp*4+r
#pragma unroll
    for (int r = 0; r < 4; ++r) {
      const int q = wave * 16 + grp * 4 + r;
      const float s = k2 - 2.0f * acc[r] - 768.0f;
      scores[(size_t)q * N_K + n0 + r16] = (_Float16)s;
    }
  }
}

// ---------------------------------------------------------------------------
// K3: per (query, quarter-slice) WG: approx top-32 candidates, then EXACT
// (double) d^2 for them. grid = 64*4 WGs of 256.
// ---------------------------------------------------------------------------
__global__ __launch_bounds__(256) void k_select(const _Float16* __restrict__ scores,
                                                const float* __restrict__ keys,
                                                const float* __restrict__ query,
                                                double* __restrict__ candD,
                                                int* __restrict__ candI) {
  const int b   = blockIdx.x >> 2;
  const int sl  = blockIdx.x & 3;
  const int tid = threadIdx.x;
  const int SLICE = N_K / 4;  // 65536

  // ---- per-thread top-8 scan of 256 scores (f16x8 vector loads) ----
  const _Float16* srow = scores + (size_t)b * N_K + (size_t)sl * SLICE;
  float bestv[8];
  int   bestn[8];
#pragma unroll
  for (int j = 0; j < 8; ++j) { bestv[j] = 1e30f; bestn[j] = -1; }
  float worst = 1e30f;
  int   wslot = 0;
  for (int it = 0; it < 32; ++it) {
    const int base = it * 2048 + tid * 8;
    f16x8 h = *reinterpret_cast<const f16x8*>(srow + base);
#pragma unroll
    for (int e = 0; e < 8; ++e) {
      float v = (float)h[e];
      if (v < worst) {
        bestv[wslot] = v; bestn[wslot] = base + e;
        worst = -1e30f;
#pragma unroll
        for (int j = 0; j < 8; ++j)
          if (bestv[j] > worst) { worst = bestv[j]; wslot = j; }
      }
    }
  }

  // ---- select slice top-32 out of 256x8 via 32 rounds of block-argmin ----
  __shared__ unsigned long long lds64[256];
  __shared__ unsigned long long winner;
  __shared__ int candShared[32];
  __shared__ double q2sh;

  unsigned long long p8[8];
#pragma unroll
  for (int j = 0; j < 8; ++j)
    p8[j] = ((unsigned long long)fkey(bestv[j]) << 32) | (unsigned int)bestn[j];
  unsigned long long myMin = p8[0];
#pragma unroll
  for (int j = 1; j < 8; ++j) myMin = umin64(myMin, p8[j]);

  for (int round = 0; round < 32; ++round) {
    lds64[tid] = myMin;
    __syncthreads();
    if (tid < 64) {
      unsigned long long m = lds64[tid];
      m = umin64(m, lds64[tid + 64]);
      m = umin64(m, lds64[tid + 128]);
      m = umin64(m, lds64[tid + 192]);
      for (int o = 32; o; o >>= 1) {
        unsigned long long other = __shfl_xor(m, o);
        m = umin64(m, other);
      }
      if (tid == 0) {
        winner = m;
        candShared[round] = (int)(m & 0xFFFFFFFFull);
      }
    }
    __syncthreads();
    const unsigned long long w = winner;
    bool changed = false;
#pragma unroll
    for (int j = 0; j < 8; ++j)
      if (p8[j] == w) { p8[j] = ~0ull; changed = true; }
    if (changed) {
      myMin = p8[0];
#pragma unroll
      for (int j = 1; j < 8; ++j) myMin = umin64(myMin, p8[j]);
    }
    __syncthreads();
  }

  // ---- exact (double) d^2 for the 32 candidates ----
  const float* qrow = query + (size_t)b * D_K;
  if (tid < 64) {
    double s = 0.0;
    for (int i = 0; i < 12; ++i) {
      float x = qrow[tid + 64 * i];
      s += (double)x * (double)x;
    }
    for (int o = 32; o; o >>= 1) s += __shfl_xor(s, o);
    if (tid == 0) q2sh = s;
  }
  __syncthreads();

  const int lane = tid & 63;
  const int wv   = tid >> 6;
  for (int cc = 0; cc < 8; ++cc) {
    const int c = wv * 8 + cc;
    const int n = candShared[c] + sl * SLICE;  // global key index
    const float* krow = keys + (size_t)n * D_K;
    double qk = 0.0, kk = 0.0;
    for (int i = 0; i < 12; ++i) {
      float kv = krow[lane + 64 * i];
      float qv = qrow[lane + 64 * i];
      qk += (double)qv * (double)kv;
      kk += (double)kv * (double)kv;
    }
    for (int o = 32; o; o >>= 1) {
      qk += __shfl_xor(qk, o);
      kk += __shfl_xor(kk, o);
    }
    if (lane == 0) {
      candD[(size_t)blockIdx.x * 32 + c] = q2sh + kk - 2.0 * qk;
      candI[(size_t)blockIdx.x * 32 + c] = n;
    }
  }
}

// ---------------------------------------------------------------------------
// K4: per query merge 4x32 exact candidates -> top-8, softmax weights, tokens.
// grid = 64 WGs of 64 (one wave).
// ---------------------------------------------------------------------------
__global__ __launch_bounds__(64) void k_topk(const double* __restrict__ candD,
                                             const int* __restrict__ candI,
                                             const int* __restrict__ values,
                                             int* __restrict__ tokOut,
                                             float* __restrict__ wOut) {
  const int b    = blockIdx.x;
  const int lane = threadIdx.x;
  double d0 = candD[(size_t)b * 128 + lane];
  int    i0 = candI[(size_t)b * 128 + lane];
  double d1 = candD[(size_t)b * 128 + 64 + lane];
  int    i1 = candI[(size_t)b * 128 + 64 + lane];

  double dist[KNN_K];
  int    idx8[KNN_K];
  for (int r = 0; r < KNN_K; ++r) {
    double dv = d0; int iv = i0;
    if (d1 < dv || (d1 == dv && i1 < iv)) { dv = d1; iv = i1; }
    for (int o = 32; o; o >>= 1) {
      double od = __shfl_xor(dv, o);
      int    oi = __shfl_xor(iv, o);
      if (od < dv || (od == dv && oi < iv)) { dv = od; iv = oi; }
    }
    dist[r] = dv; idx8[r] = iv;
    if (i0 == iv) d0 = 1e300;  // candidate indices are unique
    if (i1 == iv) d1 = 1e300;
  }

  if (lane == 0) {
    const double dmin = dist[0];
    float w[KNN_K];
    float wsum = 0.f;
    for (int r = 0; r < KNN_K; ++r) {
      w[r] = expf((float)((dmin - dist[r]) * (double)TEMP_INV));
      wsum += w[r];
    }
    const float inv = 1.0f / wsum;
    for (int r = 0; r < KNN_K; ++r) {
      tokOut[b * KNN_K + r] = values[idx8[r]];
      wOut[b * KNN_K + r]   = w[r] * inv;
    }
  }
}

// ---------------------------------------------------------------------------
// K5a: per (row, quarter) softmax stats of base_logits: slice max + sum(exp).
// grid = 64*4 WGs of 256.
// ---------------------------------------------------------------------------
__global__ __launch_bounds__(256) void k_rowstats(const float* __restrict__ base,
                                                  float* __restrict__ stats) {
  const int b   = blockIdx.x >> 2;
  const int sl  = blockIdx.x & 3;
  const int tid = threadIdx.x;
  const int start = sl * 12565;
  const int end   = (start + 12565 < V_SZ) ? start + 12565 : V_SZ;
  const float* row = base + (size_t)b * V_SZ;

  __shared__ float red[256];
  float m = -1e30f;
  for (int i = start + tid; i < end; i += 256) m = fmaxf(m, row[i]);
  red[tid] = m;
  __syncthreads();
  for (int s = 128; s; s >>= 1) {
    if (tid < s) red[tid] = fmaxf(red[tid], red[tid + s]);
    __syncthreads();
  }
  m = red[0];
  __syncthreads();

  float sum = 0.f;
  for (int i = start + tid; i < end; i += 256) sum += expf(row[i] - m);
  red[tid] = sum;
  __syncthreads();
  for (int s = 128; s; s >>= 1) {
    if (tid < s) red[tid] += red[tid + s];
    __syncthreads();
  }
  if (tid == 0) {
    stats[blockIdx.x * 2 + 0] = m;
    stats[blockIdx.x * 2 + 1] = red[0];
  }
}

// ---------------------------------------------------------------------------
// K5b: outputs. out[0:BV)=log(0.75*softmax(base)+0.25*softmax(knn));
// out[BV:2BV)=base copy; out[2BV:3BV)=log(token_probs+eps).
// grid = 64 rows * 25 segments of 2048.
// ---------------------------------------------------------------------------
__global__ __launch_bounds__(256) void k_out(const float* __restrict__ base,
                                             const float* __restrict__ stats,
                                             const int* __restrict__ tok,
                                             const float* __restrict__ wgt,
                                             float* __restrict__ out) {
  const int b   = blockIdx.x / 25;
  const int seg = blockIdx.x % 25;
  const int tid = threadIdx.x;

  float m = -1e30f;
#pragma unroll
  for (int s = 0; s < 4; ++s) m = fmaxf(m, stats[(b * 4 + s) * 2]);
  float S = 0.f;
#pragma unroll
  for (int s = 0; s < 4; ++s)
    S += stats[(b * 4 + s) * 2 + 1] * expf(stats[(b * 4 + s) * 2] - m);
  const float invS = 1.0f / S;

  int   t8[KNN_K];
  float w8[KNN_K];
#pragma unroll
  for (int j = 0; j < KNN_K; ++j) {
    t8[j] = tok[b * KNN_K + j];
    w8[j] = wgt[b * KNN_K + j];
  }
  const float knorm = 1.0f / (1.0f + (float)V_SZ * EPS_KNN);
  const size_t BV = (size_t)B_Q * V_SZ;

#pragma unroll
  for (int e = 0; e < 8; ++e) {
    const int v = seg * 2048 + e * 256 + tid;
    if (v < V_SZ) {
      const size_t o = (size_t)b * V_SZ + v;
      const float bv = base[o];
      const float pb = expf(bv - m) * invS;
      float tp = 0.f;
#pragma unroll
      for (int j = 0; j < KNN_K; ++j) tp += (t8[j] == v) ? w8[j] : 0.f;
      const float pk = (tp + EPS_KNN) * knorm;
      out[o]          = logf((1.0f - LAM) * pb + LAM * pk);
      out[BV + o]     = bv;
      out[2 * BV + o] = logf(tp + EPS_KNN);
    }
  }
}

// ---------------------------------------------------------------------------
extern "C" void kernel_launch(void* const* d_in, const int* in_sizes, int n_in,
                              void* d_out, int out_size, void* d_ws, size_t ws_size,
                              hipStream_t stream) {
  (void)in_sizes; (void)n_in; (void)out_size; (void)ws_size;
  const float* query  = (const float*)d_in[0];
  const float* base   = (const float*)d_in[1];
  const float* keys   = (const float*)d_in[2];
  const int*   values = (const int*)d_in[3];
  float* out = (float*)d_out;

  char* ws = (char*)d_ws;
  __bf16*   qbf    = (__bf16*)(ws + 0);              // 64*768*2      = 98304
  _Float16* scores = (_Float16*)(ws + 98304);        // 64*262144*2   = 33554432
  double*   candD  = (double*)(ws + 33652736);       // 256*32*8      = 65536
  int*      candI  = (int*)(ws + 33718272);          // 256*32*4      = 32768
  int*      tokOut = (int*)(ws + 33751040);          // 64*8*4        = 2048
  float*    wOut   = (float*)(ws + 33753088);        // 64*8*4        = 2048
  float*    stats  = (float*)(ws + 33755136);        // 64*4*2*4      = 2048

  k_cvt<<<192, 256, 0, stream>>>(query, qbf);
  k_gemm<<<2048, 256, 0, stream>>>(keys, qbf, scores);
  k_select<<<256, 256, 0, stream>>>(scores, keys, query, candD, candI);
  k_topk<<<64, 64, 0, stream>>>(candD, candI, values, tokOut, wOut);
  k_rowstats<<<256, 256, 0, stream>>>(base, stats);
  k_out<<<1600, 256, 0, stream>>>(base, stats, tokOut, wOut, out);
}